// Round 13
// baseline (679.346 us; speedup 1.0000x reference)
//
#include <hip/hip_runtime.h>

#define N_NODES 20000
#define D_IN    1000
#define E_EDGES 160000
#define DA      100

#define MPAD 20224    // 158 * 128 (padded rows)
#define DP   1024     // padded K / structural cols
#define DAP  128      // padded attr cols
#define MBLK 157      // 128-row blocks for attr gemm
#define NBR8 158      // 128-row blocks for structural gemm (158*128 = 20224)
#define NRB  1250     // row-blocks per graph for spmm (16 rows/block)
#define PEMAX (E_EDGES + 4 * N_NODES)   // padded edge capacity (rows padded to x4)

typedef __bf16 bf16x8 __attribute__((ext_vector_type(8)));
typedef float  f32x4  __attribute__((ext_vector_type(4)));
typedef short  short8v __attribute__((ext_vector_type(8)));

__device__ __forceinline__ short f2bf(float f) {
  __bf16 h = (__bf16)f;                 // native RNE cvt
  return *(short*)&h;
}
__device__ __forceinline__ float bf2f(short s) {
  return __uint_as_float(((unsigned)(unsigned short)s) << 16);
}

#define GLDS16(g, l) __builtin_amdgcn_global_load_lds( \
    (const __attribute__((address_space(1))) void*)(g), \
    (__attribute__((address_space(3))) void*)(l), 16, 0, 0)

// ---------------------------------------------------------------- conversions

// all-4-buffers f32->bf16 pad. 4 rows/block (1/wave), lane does units {lane, lane+64}.
__global__ void cvt_pad4_v3(const float* __restrict__ s0, const float* __restrict__ s1,
                            const float* __restrict__ s2, const float* __restrict__ s3,
                            short* __restrict__ d0, short* __restrict__ d1,
                            short* __restrict__ d2, short* __restrict__ d3) {
  const float* src; short* dst;
  switch (blockIdx.z) {
    case 0:  src = s0; dst = d0; break;
    case 1:  src = s1; dst = d1; break;
    case 2:  src = s2; dst = d2; break;
    default: src = s3; dst = d3; break;
  }
  const int lane = threadIdx.x & 63;
  const int r = blockIdx.y * 4 + (threadIdx.x >> 6);
  const int u1 = lane + 64;
  short8v o0 = {0, 0, 0, 0, 0, 0, 0, 0};
  short8v o1 = {0, 0, 0, 0, 0, 0, 0, 0};
  if (r < N_NODES) {
    const float* p0 = src + (size_t)r * D_IN + lane * 8;   // cols <= 511, always real
    float4 a0 = *(const float4*)p0;
    float4 a1 = *(const float4*)(p0 + 4);
    o0[0] = f2bf(a0.x); o0[1] = f2bf(a0.y); o0[2] = f2bf(a0.z); o0[3] = f2bf(a0.w);
    o0[4] = f2bf(a1.x); o0[5] = f2bf(a1.y); o0[6] = f2bf(a1.z); o0[7] = f2bf(a1.w);
    if (u1 < 125) {                                        // cols <= 999
      const float* p1 = src + (size_t)r * D_IN + u1 * 8;
      float4 b0 = *(const float4*)p1;
      float4 b1 = *(const float4*)(p1 + 4);
      o1[0] = f2bf(b0.x); o1[1] = f2bf(b0.y); o1[2] = f2bf(b0.z); o1[3] = f2bf(b0.w);
      o1[4] = f2bf(b1.x); o1[5] = f2bf(b1.y); o1[6] = f2bf(b1.z); o1[7] = f2bf(b1.w);
    }
  }
  *(short8v*)&dst[(size_t)r * DP + lane * 8] = o0;
  *(short8v*)&dst[(size_t)r * DP + u1 * 8] = o1;
}

__global__ void cvt_w_t2_k(const float* __restrict__ s0, const float* __restrict__ s1,
                           int K, int Nc,
                           short* __restrict__ d0, short* __restrict__ d1, int Kp) {
  const float* src = blockIdx.z ? s1 : s0;
  short* dst = blockIdx.z ? d1 : d0;
  int n = blockIdx.y;
  int k = blockIdx.x * blockDim.x + threadIdx.x;
  if (k >= Kp) return;
  float v = (k < K && n < Nc) ? src[(size_t)k * Nc + n] : 0.f;
  dst[(size_t)n * Kp + k] = f2bf(v);
}

__global__ void zero_int_k(int* p, int n) {
  int i = blockIdx.x * blockDim.x + threadIdx.x;
  if (i < n) p[i] = 0;
}

// ---------------------------------------------------------------- CSR build (padded, both graphs)

__global__ void hist2_k(const int* __restrict__ row0, const int* __restrict__ row1, int E,
                        int* __restrict__ deg0, int* __restrict__ deg1) {
  int e = blockIdx.x * blockDim.x + threadIdx.x;
  if (e < E) atomicAdd(&deg0[row0[e]], 1);
  else if (e < 2 * E) atomicAdd(&deg1[row1[e - E]], 1);
}

#define SCAN_T 1024
#define SCAN_C 20
__launch_bounds__(SCAN_T)
__global__ void scan_pad2_k(const int* __restrict__ dg0, const int* __restrict__ dg1, int n,
                            int* __restrict__ p0, int* __restrict__ p1) {
  const int* deg = blockIdx.x ? dg1 : dg0;
  int* poffs = blockIdx.x ? p1 : p0;
  __shared__ int lds[SCAN_T];
  int t = threadIdx.x;
  int base = t * SCAN_C;
  int v[SCAN_C];
  int s = 0;
#pragma unroll
  for (int i = 0; i < SCAN_C; ++i) {
    int idx = base + i;
    int x = (idx < n) ? ((deg[idx] + 3) & ~3) : 0;
    s += x;
    v[i] = s;
  }
  lds[t] = s;
  __syncthreads();
  for (int off = 1; off < SCAN_T; off <<= 1) {
    int add = (t >= off) ? lds[t - off] : 0;
    __syncthreads();
    lds[t] += add;
    __syncthreads();
  }
  int prefix = lds[t] - s;
#pragma unroll
  for (int i = 0; i < SCAN_C; ++i) {
    int idx = base + i;
    if (idx < n) poffs[idx + 1] = v[i] + prefix;
  }
  if (t == 0) poffs[0] = 0;
}

__global__ void scatter_pack2_k(const int* __restrict__ row0, const int* __restrict__ col0,
                                const float* __restrict__ val0,
                                const int* __restrict__ row1, const int* __restrict__ col1,
                                const float* __restrict__ val1, int E,
                                const int* __restrict__ po0, const int* __restrict__ po1,
                                int* __restrict__ cur0, int* __restrict__ cur1,
                                int2* __restrict__ pk0, int2* __restrict__ pk1) {
  int e = blockIdx.x * blockDim.x + threadIdx.x;
  if (e < E) {
    int r = row0[e];
    int p = atomicAdd(&cur0[r], 1);
    pk0[po0[r] + p] = make_int2(col0[e], __float_as_int(val0[e]));
  } else if (e < 2 * E) {
    int ee = e - E;
    int r = row1[ee];
    int p = atomicAdd(&cur1[r], 1);
    pk1[po1[r] + p] = make_int2(col1[ee], __float_as_int(val1[ee]));
  }
}

// ---------------------------------------------------------------- structural GEMM v3: 128x256 tile, 32 phases
// C[M x 1024] = A[M x 1024] * Bt[1024 x 1024]^T, bf16, f32 accum, bf16 out.
// 512 thr = 8 waves (2M x 4N), 64x64 out/wave, BK=64 split in 2 k-slices.
// LDS: 4 slots x (A 8KB + B 16KB) = 96 KB. Phase p (0..31): tile p>>1, ks p&1,
// kc = p*32. Uniform 3 gload_lds per phase (A=1, B=2). Stage phase p+3 at p
// (slot (p+3)&3 last read at p-1, consumed before its end barrier -> safe).
// Steady vmcnt(6) = 2 phases in flight; tail 6/3/0 at p=28/29/30.
// Swizzle: 16B-chunk ^= (row>>1)&3 on both stage-source and ds_read.
__launch_bounds__(512, 1)
__global__ void gemm8p2_k(const short* __restrict__ A0, const short* __restrict__ A1, int lda,
                          const short* __restrict__ Bt0, const short* __restrict__ Bt1, int ldb,
                          short* __restrict__ C0, short* __restrict__ C1, int ldc,
                          int nbCol, int nbRow) {
  __shared__ short sA[4][4096];   // 32 KB
  __shared__ short sB[4][8192];   // 64 KB

  // XCD-aware bijective remap (cols fastest within chunk)
  int orig = blockIdx.x;
  int nwg = gridDim.x;
  int q = nwg >> 3, rr = nwg & 7;
  int xcd = orig & 7, idx = orig >> 3;
  int wg = (xcd < rr ? xcd * (q + 1) : rr * (q + 1) + (xcd - rr) * q) + idx;
  int colB = wg % nbCol;
  int t2 = wg / nbCol;
  int rowB = t2 % nbRow;
  int z = t2 / nbRow;

  const short* A  = z ? A1 : A0;
  const short* Bt = z ? Bt1 : Bt0;
  short* C        = z ? C1 : C0;

  const int tid  = threadIdx.x;
  const int lane = tid & 63;
  const int wid  = tid >> 6;
  const int wm   = wid >> 2;      // 0..1
  const int wn   = wid & 3;       // 0..3
  const int rowBase = rowB * 128;
  const int colBase = colB * 256;

  // stage source: wave covers 16 rows (lane>>2), chunk (lane&3)^((lane>>3)&3)
  const int sC = (lane & 3) ^ ((lane >> 3) & 3);
  const short* baseA  = A  + (size_t)(rowBase + wid * 16 + (lane >> 2)) * lda + sC * 8;
  const short* baseB0 = Bt + (size_t)(colBase + wid * 16 + (lane >> 2)) * ldb + sC * 8;
  const short* baseB1 = Bt + (size_t)(colBase + 128 + wid * 16 + (lane >> 2)) * ldb + sC * 8;

  // read-side swizzled offsets (shorts within a slot: [rows][32 cols])
  int offA[4], offB[4];
#pragma unroll
  for (int m = 0; m < 4; ++m) {
    int row = wm * 64 + m * 16 + (lane & 15);
    int ch = (lane >> 4) ^ ((row >> 1) & 3);
    offA[m] = row * 32 + ch * 8;
  }
#pragma unroll
  for (int n = 0; n < 4; ++n) {
    int row = wn * 64 + n * 16 + (lane & 15);
    int ch = (lane >> 4) ^ ((row >> 1) & 3);
    offB[n] = row * 32 + ch * 8;
  }

  f32x4 acc[4][4];
#pragma unroll
  for (int m = 0; m < 4; ++m)
#pragma unroll
    for (int n = 0; n < 4; ++n)
      acc[m][n] = (f32x4){0.f, 0.f, 0.f, 0.f};

#define STAGE_P(p) do { \
    int kc_ = (p) * 32; \
    GLDS16(baseA  + kc_, &sA[(p) & 3][wid * 512]); \
    GLDS16(baseB0 + kc_, &sB[(p) & 3][wid * 512]); \
    GLDS16(baseB1 + kc_, &sB[(p) & 3][4096 + wid * 512]); \
  } while (0)

  // prologue: stage phases 0..2 (9 loads), wait so phase 0 landed
  STAGE_P(0); STAGE_P(1); STAGE_P(2);
  asm volatile("s_waitcnt vmcnt(6)" ::: "memory");
  __builtin_amdgcn_s_barrier();

  for (int p = 0; p < 32; ++p) {
    const short* pA = &sA[p & 3][0];
    const short* pB = &sB[p & 3][0];
    bf16x8 af[4], bv[4];
#pragma unroll
    for (int m = 0; m < 4; ++m) af[m] = *(const bf16x8*)&pA[offA[m]];
#pragma unroll
    for (int n = 0; n < 4; ++n) bv[n] = *(const bf16x8*)&pB[offB[n]];
    if (p < 29) STAGE_P(p + 3);
    __builtin_amdgcn_s_barrier();
    __builtin_amdgcn_s_setprio(1);
#pragma unroll
    for (int m = 0; m < 4; ++m)
#pragma unroll
      for (int n = 0; n < 4; ++n)
        acc[m][n] = __builtin_amdgcn_mfma_f32_16x16x32_bf16(af[m], bv[n], acc[m][n], 0, 0, 0);
    __builtin_amdgcn_s_setprio(0);
    if (p < 29)       { asm volatile("s_waitcnt vmcnt(6)" ::: "memory"); }
    else if (p == 29) { asm volatile("s_waitcnt vmcnt(3)" ::: "memory"); }
    else if (p == 30) { asm volatile("s_waitcnt vmcnt(0)" ::: "memory"); }
    __builtin_amdgcn_s_barrier();
  }
#undef STAGE_P

  // C write: D layout col=lane&15, row=(lane>>4)*4+reg
#pragma unroll
  for (int m = 0; m < 4; ++m) {
#pragma unroll
    for (int n = 0; n < 4; ++n) {
      int r0 = rowBase + wm * 64 + m * 16 + (lane >> 4) * 4;
      int c  = colBase + wn * 64 + n * 16 + (lane & 15);
#pragma unroll
      for (int reg = 0; reg < 4; ++reg)
        C[(size_t)(r0 + reg) * ldc + c] = f2bf(acc[m][n][reg]);
    }
  }
}

// ---------------------------------------------------------------- small GEMM (128x128, attr branch)
__launch_bounds__(256, 2)
__global__ void gemm_bf16_k(const short* __restrict__ A0, const short* __restrict__ A1, int lda,
                            const short* __restrict__ Bt0, const short* __restrict__ Bt1, int ldb,
                            short* __restrict__ C0, short* __restrict__ C1, int ldc, int K,
                            int nbCol, int nbRow) {
  __shared__ short As[128 * 64];
  __shared__ short Bs[128 * 64];

  int orig = blockIdx.x;
  int nwg = gridDim.x;
  int q = nwg >> 3, rr = nwg & 7;
  int xcd = orig & 7, idx = orig >> 3;
  int wg = (xcd < rr ? xcd * (q + 1) : rr * (q + 1) + (xcd - rr) * q) + idx;
  int colB = wg % nbCol;
  int t2   = wg / nbCol;
  int rowB = t2 % nbRow;
  int z    = t2 / nbRow;

  const short* A  = z ? A1 : A0;
  const short* Bt = z ? Bt1 : Bt0;
  short* C        = z ? C1 : C0;

  const int tid  = threadIdx.x;
  const int lane = tid & 63;
  const int wid  = tid >> 6;
  const int wr   = wid >> 1;
  const int wc   = wid & 1;
  const int rowBase = rowB * 128;
  const int colBase = colB * 128;

  const int lrow = lane >> 3;
  const int kofs = (lane & 7) * 8;

  f32x4 acc[4][4];
#pragma unroll
  for (int m = 0; m < 4; ++m)
#pragma unroll
    for (int n = 0; n < 4; ++n)
      acc[m][n] = (f32x4){0.f, 0.f, 0.f, 0.f};

  for (int k0 = 0; k0 < K; k0 += 64) {
#pragma unroll
    for (int c = 0; c < 4; ++c) {
      int chunk = wid * 4 + c;
      int r = chunk * 8 + lrow;
      const short* g = A + (size_t)(rowBase + r) * lda + k0 + kofs;
      GLDS16(g, &As[chunk * 8 * 64]);
    }
#pragma unroll
    for (int c = 0; c < 4; ++c) {
      int chunk = wid * 4 + c;
      int r = chunk * 8 + lrow;
      const short* g = Bt + (size_t)(colBase + r) * ldb + k0 + kofs;
      GLDS16(g, &Bs[chunk * 8 * 64]);
    }
    __syncthreads();

    bf16x8 af[2][4], bfr[2][4];
#pragma unroll
    for (int kk = 0; kk < 2; ++kk) {
#pragma unroll
      for (int i = 0; i < 4; ++i) {
        int ar = wr * 64 + i * 16 + (lane & 15);
        af[kk][i]  = *(const bf16x8*)&As[ar * 64 + kk * 32 + (lane >> 4) * 8];
        int br = wc * 64 + i * 16 + (lane & 15);
        bfr[kk][i] = *(const bf16x8*)&Bs[br * 64 + kk * 32 + (lane >> 4) * 8];
      }
    }
#pragma unroll
    for (int kk = 0; kk < 2; ++kk)
#pragma unroll
      for (int m = 0; m < 4; ++m)
#pragma unroll
        for (int n = 0; n < 4; ++n)
          acc[m][n] = __builtin_amdgcn_mfma_f32_16x16x32_bf16(
              af[kk][m], bfr[kk][n], acc[m][n], 0, 0, 0);
    __syncthreads();
  }

#pragma unroll
  for (int m = 0; m < 4; ++m) {
#pragma unroll
    for (int n = 0; n < 4; ++n) {
      int row0 = rowBase + wr * 64 + m * 16 + (lane >> 4) * 4;
      int col  = colBase + wc * 64 + n * 16 + (lane & 15);
#pragma unroll
      for (int reg = 0; reg < 4; ++reg)
        C[(size_t)(row0 + reg) * ldc + col] = f2bf(acc[m][n][reg]);
    }
  }
}

// ---------------------------------------------------------------- SpMM + ReLU (v5: col-chunked, XCD-pinned)
template<int NCHUNK, int MODE>
__launch_bounds__(256)
__global__ void spmm_v5(const int* __restrict__ po0, const int* __restrict__ po1,
                        const int2* __restrict__ pk0, const int2* __restrict__ pk1,
                        const short* __restrict__ S0, const short* __restrict__ S1, int ldS,
                        short* __restrict__ oB0, short* __restrict__ oB1, int ldB,
                        float* __restrict__ oF0, float* __restrict__ oF1, int outCols) {
  int orig = blockIdx.x;
  int chunk, graph, rowBlk;
  if (NCHUNK == 8) {
    chunk = orig & 7;
    int idx = orig >> 3;
    graph = idx / NRB;
    rowBlk = idx - graph * NRB;
  } else {
    chunk = 0;
    graph = orig / NRB;
    rowBlk = orig - graph * NRB;
  }
  const int* poffs   = graph ? po1 : po0;
  const int2* packed = graph ? pk1 : pk0;
  const short* S     = graph ? S1 : S0;
  short* outB        = graph ? oB1 : oB0;
  float* outF        = graph ? oF1 : oF0;

  const int lane16 = threadIdx.x & 15;
  const int rowloc = threadIdx.x >> 4;
  const int r  = rowBlk * 16 + rowloc;
  const int c0 = chunk * 128 + lane16 * 8;

  int e0 = poffs[r], e1 = poffs[r + 1];
  float acc[8];
#pragma unroll
  for (int j = 0; j < 8; ++j) acc[j] = 0.f;

  for (int i = e0; i < e1; i += 4) {
    const int4* p4 = (const int4*)&packed[i];
    int4 a = p4[0];
    int4 b = p4[1];
    short8v s0 = *(const short8v*)&S[(size_t)a.x * ldS + c0];
    short8v s1 = *(const short8v*)&S[(size_t)a.z * ldS + c0];
    short8v s2 = *(const short8v*)&S[(size_t)b.x * ldS + c0];
    short8v s3 = *(const short8v*)&S[(size_t)b.z * ldS + c0];
    float v0 = __int_as_float(a.y);
    float v1 = __int_as_float(a.w);
    float v2 = __int_as_float(b.y);
    float v3 = __int_as_float(b.w);
#pragma unroll
    for (int j = 0; j < 8; ++j) {
      acc[j] += v0 * bf2f(s0[j]);
      acc[j] += v1 * bf2f(s1[j]);
      acc[j] += v2 * bf2f(s2[j]);
      acc[j] += v3 * bf2f(s3[j]);
    }
  }
#pragma unroll
  for (int j = 0; j < 8; ++j) acc[j] = fmaxf(acc[j], 0.f);

  if (MODE == 0) {
    short8v o;
#pragma unroll
    for (int j = 0; j < 8; ++j) o[j] = f2bf(acc[j]);
    *(short8v*)&outB[(size_t)r * ldB + c0] = o;
  } else {
#pragma unroll
    for (int j = 0; j < 8; ++j)
      if (c0 + j < outCols)
        outF[(size_t)r * outCols + c0 + j] = acc[j];
  }
}

// ---------------------------------------------------------------- row l2 norm (z=2), vectorized short4 reads
__launch_bounds__(256)
__global__ void l2norm2_k(const short* __restrict__ H0, const short* __restrict__ H1, int ldH,
                          float* __restrict__ o0, float* __restrict__ o1, int cols) {
  const short* H = blockIdx.y ? H1 : H0;
  float* out = blockIdx.y ? o1 : o0;
  __shared__ float red[4];
  int r = blockIdx.x;
  int t = threadIdx.x;
  short4 v = ((const short4*)(H + (size_t)r * ldH))[t];
  float f0 = bf2f(v.x), f1 = bf2f(v.y), f2 = bf2f(v.z), f3 = bf2f(v.w);
  float s = f0 * f0 + f1 * f1 + f2 * f2 + f3 * f3;
  for (int off = 32; off >= 1; off >>= 1) s += __shfl_down(s, off, 64);
  if ((t & 63) == 0) red[t >> 6] = s;
  __syncthreads();
  float tot = red[0] + red[1] + red[2] + red[3];
  float inv = 1.f / fmaxf(sqrtf(tot), 1e-12f);
  int c0 = t * 4;
  float vals[4] = {f0, f1, f2, f3};
#pragma unroll
  for (int j = 0; j < 4; ++j)
    if (c0 + j < cols)
      out[(size_t)r * cols + c0 + j] = vals[j] * inv;
}

// ---------------------------------------------------------------- launch

extern "C" void kernel_launch(void* const* d_in, const int* in_sizes, int n_in,
                              void* d_out, int out_size, void* d_ws, size_t ws_size,
                              hipStream_t stream) {
  const float* emb_sr  = (const float*)d_in[0];
  const float* emb_tg  = (const float*)d_in[1];
  const float* attr_sr = (const float*)d_in[2];
  const float* attr_tg = (const float*)d_in[3];
  const int*   row_sr  = (const int*)d_in[4];
  const int*   col_sr  = (const int*)d_in[5];
  const float* vals_sr = (const float*)d_in[6];
  const int*   row_tg  = (const int*)d_in[7];
  const int*   col_tg  = (const int*)d_in[8];
  const float* vals_tg = (const float*)d_in[9];
  const float* W_s0    = (const float*)d_in[10];
  const float* W_s1    = (const float*)d_in[11];
  const float* W_a11   = (const float*)d_in[12];
  const float* W_a12   = (const float*)d_in[13];
  const float* W_a2    = (const float*)d_in[14];

  const int N = N_NODES, Dd = D_IN, E = E_EDGES;

  char* ws = (char*)d_ws;
  size_t off = 0;
  auto alloc = [&](size_t bytes) -> void* {
    void* p = ws + off;
    off += (bytes + 255) & ~(size_t)255;
    return p;
  };
  short* X0 = (short*)alloc((size_t)MPAD * DP * 2);
  short* X1 = (short*)alloc((size_t)MPAD * DP * 2);
  short* T0 = (short*)alloc((size_t)MPAD * DP * 2);
  short* T1 = (short*)alloc((size_t)MPAD * DP * 2);
  short* Y0 = (short*)alloc((size_t)MPAD * DP * 2);   // attr bf16 (early convert)
  short* Y1 = (short*)alloc((size_t)MPAD * DP * 2);
  short* Ws0t  = (short*)alloc((size_t)DP * DP * 2);
  short* Ws1t  = (short*)alloc((size_t)DP * DP * 2);
  short* Wa11t = (short*)alloc((size_t)DAP * DP * 2);
  short* Wa12t = (short*)alloc((size_t)DAP * DP * 2);
  short* Wa2t  = (short*)alloc((size_t)DAP * DAP * 2);
  int*  ibuf    = (int*)alloc((size_t)4 * N * 4);
  int2* pack_sr = (int2*)alloc((size_t)PEMAX * 8);
  int2* pack_tg = (int2*)alloc((size_t)PEMAX * 8);
  int*  poffs_sr = (int*)alloc((size_t)(N + 1) * 4);
  int*  poffs_tg = (int*)alloc((size_t)(N + 1) * 4);
  if (off > ws_size) return;

  int* deg_sr = ibuf;
  int* cur_sr = ibuf + N;
  int* deg_tg = ibuf + 2 * N;
  int* cur_tg = ibuf + 3 * N;
  const int ZERO_N = 4 * N + 2 * (PEMAX * 2);

  float* out_sr  = (float*)d_out;
  float* out_tg  = out_sr + (size_t)N * Dd;
  float* out_sra = out_tg + (size_t)N * Dd;
  float* out_tga = out_sra + (size_t)N * DA;

  // ---- padded-CSR build, both graphs batched
  zero_int_k<<<dim3((ZERO_N + 255) / 256), 256, 0, stream>>>(ibuf, ZERO_N);
  hist2_k<<<dim3((2 * E + 255) / 256), 256, 0, stream>>>(row_sr, row_tg, E, deg_sr, deg_tg);
  scan_pad2_k<<<2, SCAN_T, 0, stream>>>(deg_sr, deg_tg, N, poffs_sr, poffs_tg);
  scatter_pack2_k<<<dim3((2 * E + 255) / 256), 256, 0, stream>>>(
      row_sr, col_sr, vals_sr, row_tg, col_tg, vals_tg, E,
      poffs_sr, poffs_tg, cur_sr, cur_tg, pack_sr, pack_tg);

  // ---- all input conversions + weights
  cvt_pad4_v3<<<dim3(1, MPAD / 4, 4), 256, 0, stream>>>(emb_sr, emb_tg, attr_sr, attr_tg,
                                                        X0, X1, Y0, Y1);
  cvt_w_t2_k<<<dim3(DP / 256, DP, 2), 256, 0, stream>>>(W_s0, W_s1, Dd, Dd, Ws0t, Ws1t, DP);
  cvt_w_t2_k<<<dim3(DP / 256, DAP, 2), 256, 0, stream>>>(W_a11, W_a12, Dd, DA, Wa11t, Wa12t, DP);
  cvt_w_t2_k<<<dim3(1, DAP, 1), 256, 0, stream>>>(W_a2, W_a2, DA, DA, Wa2t, Wa2t, DAP);

  // ---- structural branch: 128x256-tile 32-phase GEMM (158x4x2 = 1264 blocks, %8==0)
  gemm8p2_k<<<dim3(NBR8 * 4 * 2), 512, 0, stream>>>(X0, X1, DP, Ws0t, Ws0t, DP,
                                                    T0, T1, DP, 4, NBR8);
  spmm_v5<8, 0><<<dim3(8 * 2 * NRB), 256, 0, stream>>>(
      poffs_sr, poffs_tg, pack_sr, pack_tg, T0, T1, DP, X0, X1, DP, nullptr, nullptr, 0);
  gemm8p2_k<<<dim3(NBR8 * 4 * 2), 512, 0, stream>>>(X0, X1, DP, Ws1t, Ws1t, DP,
                                                    T0, T1, DP, 4, NBR8);
  spmm_v5<8, 0><<<dim3(8 * 2 * NRB), 256, 0, stream>>>(
      poffs_sr, poffs_tg, pack_sr, pack_tg, T0, T1, DP, X0, X1, DP, nullptr, nullptr, 0);
  l2norm2_k<<<dim3(N, 2), 256, 0, stream>>>(X0, X1, DP, out_sr, out_tg, Dd);

  // ---- attribute branch (A = Y, pre-converted; compact stride DAP)
  gemm_bf16_k<<<dim3(1 * MBLK * 2), 256, 0, stream>>>(Y0, Y1, DP, Wa11t, Wa12t, DP,
                                                      T0, T1, DAP, DP, 1, MBLK);
  spmm_v5<1, 0><<<dim3(2 * NRB), 256, 0, stream>>>(
      poffs_sr, poffs_tg, pack_sr, pack_tg, T0, T1, DAP, X0, X1, DAP, nullptr, nullptr, 0);
  gemm_bf16_k<<<dim3(1 * MBLK * 2), 256, 0, stream>>>(X0, X1, DAP, Wa2t, Wa2t, DAP,
                                                      T0, T1, DAP, DAP, 1, MBLK);
  spmm_v5<1, 1><<<dim3(2 * NRB), 256, 0, stream>>>(
      poffs_sr, poffs_tg, pack_sr, pack_tg, T0, T1, DAP, nullptr, nullptr, 0, out_sra, out_tga, DA);
}

// Round 14
// 644.156 us; speedup vs baseline: 1.0546x; 1.0546x over previous
//
#include <hip/hip_runtime.h>

#define N_NODES 20000
#define D_IN    1000
#define E_EDGES 160000
#define DA      100

#define MPAD 20224    // 79 * 256 (padded rows for 256-tile GEMM)
#define DP   1024     // padded K / structural cols
#define DAP  128      // padded attr cols
#define MBLK 157      // 128-row blocks for attr gemm
#define NRB  1250     // 16-row blocks per graph (attr spmm)
#define NRB32 625     // 32-row blocks per graph (structural spmm)
#define PEMAX (E_EDGES + 4 * N_NODES)   // padded edge capacity (rows padded to x4)

typedef __bf16 bf16x8 __attribute__((ext_vector_type(8)));
typedef float  f32x4  __attribute__((ext_vector_type(4)));
typedef short  short8v __attribute__((ext_vector_type(8)));

__device__ __forceinline__ short f2bf(float f) {
  __bf16 h = (__bf16)f;                 // native RNE cvt
  return *(short*)&h;
}
__device__ __forceinline__ float bf2f(short s) {
  return __uint_as_float(((unsigned)(unsigned short)s) << 16);
}

#define GLDS16(g, l) __builtin_amdgcn_global_load_lds( \
    (const __attribute__((address_space(1))) void*)(g), \
    (__attribute__((address_space(3))) void*)(l), 16, 0, 0)

// ---------------------------------------------------------------- conversions

// all-4-buffers f32->bf16 pad. 4 rows/block (1/wave), lane does units {lane, lane+64}.
__global__ void cvt_pad4_v3(const float* __restrict__ s0, const float* __restrict__ s1,
                            const float* __restrict__ s2, const float* __restrict__ s3,
                            short* __restrict__ d0, short* __restrict__ d1,
                            short* __restrict__ d2, short* __restrict__ d3) {
  const float* src; short* dst;
  switch (blockIdx.z) {
    case 0:  src = s0; dst = d0; break;
    case 1:  src = s1; dst = d1; break;
    case 2:  src = s2; dst = d2; break;
    default: src = s3; dst = d3; break;
  }
  const int lane = threadIdx.x & 63;
  const int r = blockIdx.y * 4 + (threadIdx.x >> 6);
  const int u1 = lane + 64;
  short8v o0 = {0, 0, 0, 0, 0, 0, 0, 0};
  short8v o1 = {0, 0, 0, 0, 0, 0, 0, 0};
  if (r < N_NODES) {
    const float* p0 = src + (size_t)r * D_IN + lane * 8;   // cols <= 511, always real
    float4 a0 = *(const float4*)p0;
    float4 a1 = *(const float4*)(p0 + 4);
    o0[0] = f2bf(a0.x); o0[1] = f2bf(a0.y); o0[2] = f2bf(a0.z); o0[3] = f2bf(a0.w);
    o0[4] = f2bf(a1.x); o0[5] = f2bf(a1.y); o0[6] = f2bf(a1.z); o0[7] = f2bf(a1.w);
    if (u1 < 125) {                                        // cols <= 999
      const float* p1 = src + (size_t)r * D_IN + u1 * 8;
      float4 b0 = *(const float4*)p1;
      float4 b1 = *(const float4*)(p1 + 4);
      o1[0] = f2bf(b0.x); o1[1] = f2bf(b0.y); o1[2] = f2bf(b0.z); o1[3] = f2bf(b0.w);
      o1[4] = f2bf(b1.x); o1[5] = f2bf(b1.y); o1[6] = f2bf(b1.z); o1[7] = f2bf(b1.w);
    }
  }
  *(short8v*)&dst[(size_t)r * DP + lane * 8] = o0;
  *(short8v*)&dst[(size_t)r * DP + u1 * 8] = o1;
}

__global__ void cvt_w_t2_k(const float* __restrict__ s0, const float* __restrict__ s1,
                           int K, int Nc,
                           short* __restrict__ d0, short* __restrict__ d1, int Kp) {
  const float* src = blockIdx.z ? s1 : s0;
  short* dst = blockIdx.z ? d1 : d0;
  int n = blockIdx.y;
  int k = blockIdx.x * blockDim.x + threadIdx.x;
  if (k >= Kp) return;
  float v = (k < K && n < Nc) ? src[(size_t)k * Nc + n] : 0.f;
  dst[(size_t)n * Kp + k] = f2bf(v);
}

__global__ void zero_int_k(int* p, int n) {
  int i = blockIdx.x * blockDim.x + threadIdx.x;
  if (i < n) p[i] = 0;
}

// ---------------------------------------------------------------- CSR build (padded, both graphs)

__global__ void hist2_k(const int* __restrict__ row0, const int* __restrict__ row1, int E,
                        int* __restrict__ deg0, int* __restrict__ deg1) {
  int e = blockIdx.x * blockDim.x + threadIdx.x;
  if (e < E) atomicAdd(&deg0[row0[e]], 1);
  else if (e < 2 * E) atomicAdd(&deg1[row1[e - E]], 1);
}

#define SCAN_T 1024
#define SCAN_C 20
__launch_bounds__(SCAN_T)
__global__ void scan_pad2_k(const int* __restrict__ dg0, const int* __restrict__ dg1, int n,
                            int* __restrict__ p0, int* __restrict__ p1) {
  const int* deg = blockIdx.x ? dg1 : dg0;
  int* poffs = blockIdx.x ? p1 : p0;
  __shared__ int lds[SCAN_T];
  int t = threadIdx.x;
  int base = t * SCAN_C;
  int v[SCAN_C];
  int s = 0;
#pragma unroll
  for (int i = 0; i < SCAN_C; ++i) {
    int idx = base + i;
    int x = (idx < n) ? ((deg[idx] + 3) & ~3) : 0;
    s += x;
    v[i] = s;
  }
  lds[t] = s;
  __syncthreads();
  for (int off = 1; off < SCAN_T; off <<= 1) {
    int add = (t >= off) ? lds[t - off] : 0;
    __syncthreads();
    lds[t] += add;
    __syncthreads();
  }
  int prefix = lds[t] - s;
#pragma unroll
  for (int i = 0; i < SCAN_C; ++i) {
    int idx = base + i;
    if (idx < n) poffs[idx + 1] = v[i] + prefix;
  }
  if (t == 0) poffs[0] = 0;
}

__global__ void scatter_pack2_k(const int* __restrict__ row0, const int* __restrict__ col0,
                                const float* __restrict__ val0,
                                const int* __restrict__ row1, const int* __restrict__ col1,
                                const float* __restrict__ val1, int E,
                                const int* __restrict__ po0, const int* __restrict__ po1,
                                int* __restrict__ cur0, int* __restrict__ cur1,
                                int2* __restrict__ pk0, int2* __restrict__ pk1) {
  int e = blockIdx.x * blockDim.x + threadIdx.x;
  if (e < E) {
    int r = row0[e];
    int p = atomicAdd(&cur0[r], 1);
    pk0[po0[r] + p] = make_int2(col0[e], __float_as_int(val0[e]));
  } else if (e < 2 * E) {
    int ee = e - E;
    int r = row1[ee];
    int p = atomicAdd(&cur1[r], 1);
    pk1[po1[r] + p] = make_int2(col1[ee], __float_as_int(val1[ee]));
  }
}

// ---------------------------------------------------------------- 8-phase 256x256 GEMM (structural, r9 best)
__launch_bounds__(512, 1)
__global__ void gemm8p_k(const short* __restrict__ A0, const short* __restrict__ A1, int lda,
                         const short* __restrict__ Bt0, const short* __restrict__ Bt1, int ldb,
                         short* __restrict__ C0, short* __restrict__ C1, int ldc,
                         int nbCol, int nbRow) {
  __shared__ short lds[8][8192];   // 8 x 16 KB = 128 KB

  int orig = blockIdx.x;
  int nwg = gridDim.x;
  int q = nwg >> 3, rr = nwg & 7;
  int xcd = orig & 7, idx = orig >> 3;
  int wg = (xcd < rr ? xcd * (q + 1) : rr * (q + 1) + (xcd - rr) * q) + idx;
  int colB = wg % nbCol;
  int t2 = wg / nbCol;
  int rowB = t2 % nbRow;
  int z = t2 / nbRow;

  const short* A  = z ? A1 : A0;
  const short* Bt = z ? Bt1 : Bt0;
  short* C        = z ? C1 : C0;

  const int tid  = threadIdx.x;
  const int lane = tid & 63;
  const int wid  = tid >> 6;
  const int wm   = wid >> 2;
  const int wn   = wid & 3;
  const int rowBase = rowB * 256;
  const int colBase = colB * 256;

  const int sC = (lane & 3) ^ ((lane >> 3) & 3);
  const short* baseA = A  + (size_t)(rowBase + wid * 32 + (lane >> 2)) * lda + sC * 8;
  const short* baseB = Bt + (size_t)(colBase + wid * 32 + (lane >> 2)) * ldb + sC * 8;

  const int chunkR = (lane >> 4) ^ ((lane >> 1) & 3);
  const int offA = (wm * 128 + (lane & 15)) * 32 + chunkR * 8;
  const int offB = (wn * 64  + (lane & 15)) * 32 + chunkR * 8;

  f32x4 acc[8][4];
#pragma unroll
  for (int m = 0; m < 8; ++m)
#pragma unroll
    for (int n = 0; n < 4; ++n)
      acc[m][n] = (f32x4){0.f, 0.f, 0.f, 0.f};

#define STAGE_HALF(h) do { \
    int tt_ = (h) >> 2; \
    int kc_ = tt_ * 64 + (((h) >> 1) & 1) * 32; \
    short* dst_ = &lds[(h) & 7][wid * 1024]; \
    if ((h) & 1) { GLDS16(baseB + kc_, dst_); GLDS16(baseB + kc_ + 16 * ldb, dst_ + 512); } \
    else         { GLDS16(baseA + kc_, dst_); GLDS16(baseA + kc_ + 16 * lda, dst_ + 512); } \
  } while (0)

  STAGE_HALF(0); STAGE_HALF(1); STAGE_HALF(2); STAGE_HALF(3); STAGE_HALF(4);
  asm volatile("s_waitcnt vmcnt(6)" ::: "memory");
  __builtin_amdgcn_s_barrier();

  bf16x8 bv[4];
  for (int t = 0; t < 16; ++t) {
    const int s0 = (4 * t) & 7;
    const int s1 = (4 * t + 2) & 7;

    { // P0: ks=0, qm=0
      const short* pA = &lds[s0][0];
      const short* pB = &lds[s0 + 1][0];
      bf16x8 af[4];
#pragma unroll
      for (int n = 0; n < 4; ++n) bv[n] = *(const bf16x8*)&pB[offB + n * 512];
#pragma unroll
      for (int m = 0; m < 4; ++m) af[m] = *(const bf16x8*)&pA[offA + m * 512];
      { int h = 4 * t + 5; if (h < 64) STAGE_HALF(h); }
      __builtin_amdgcn_s_barrier();
      __builtin_amdgcn_s_setprio(1);
#pragma unroll
      for (int m = 0; m < 4; ++m)
#pragma unroll
        for (int n = 0; n < 4; ++n)
          acc[m][n] = __builtin_amdgcn_mfma_f32_16x16x32_bf16(af[m], bv[n], acc[m][n], 0, 0, 0);
      __builtin_amdgcn_s_setprio(0);
      __builtin_amdgcn_s_barrier();
    }
    { // P1: ks=0, qm=1 (B from regs)
      const short* pA = &lds[s0][0];
      bf16x8 af[4];
#pragma unroll
      for (int m = 0; m < 4; ++m) af[m] = *(const bf16x8*)&pA[offA + (4 + m) * 512];
      { int h = 4 * t + 6; if (h < 64) STAGE_HALF(h); }
      __builtin_amdgcn_s_barrier();
      __builtin_amdgcn_s_setprio(1);
#pragma unroll
      for (int m = 0; m < 4; ++m)
#pragma unroll
        for (int n = 0; n < 4; ++n)
          acc[4 + m][n] = __builtin_amdgcn_mfma_f32_16x16x32_bf16(af[m], bv[n], acc[4 + m][n], 0, 0, 0);
      __builtin_amdgcn_s_setprio(0);
      if (t < 15) { asm volatile("s_waitcnt vmcnt(6)" ::: "memory"); }
      else        { asm volatile("s_waitcnt vmcnt(0)" ::: "memory"); }
      __builtin_amdgcn_s_barrier();
    }
    { // P2: ks=1, qm=0
      const short* pA = &lds[s1][0];
      const short* pB = &lds[s1 + 1][0];
      bf16x8 af[4];
#pragma unroll
      for (int n = 0; n < 4; ++n) bv[n] = *(const bf16x8*)&pB[offB + n * 512];
#pragma unroll
      for (int m = 0; m < 4; ++m) af[m] = *(const bf16x8*)&pA[offA + m * 512];
      { int h = 4 * t + 7; if (h < 64) STAGE_HALF(h); }
      __builtin_amdgcn_s_barrier();
      __builtin_amdgcn_s_setprio(1);
#pragma unroll
      for (int m = 0; m < 4; ++m)
#pragma unroll
        for (int n = 0; n < 4; ++n)
          acc[m][n] = __builtin_amdgcn_mfma_f32_16x16x32_bf16(af[m], bv[n], acc[m][n], 0, 0, 0);
      __builtin_amdgcn_s_setprio(0);
      __builtin_amdgcn_s_barrier();
    }
    { // P3: ks=1, qm=1
      const short* pA = &lds[s1][0];
      bf16x8 af[4];
#pragma unroll
      for (int m = 0; m < 4; ++m) af[m] = *(const bf16x8*)&pA[offA + (4 + m) * 512];
      { int h = 4 * t + 8; if (h < 64) STAGE_HALF(h); }
      __builtin_amdgcn_s_barrier();
      __builtin_amdgcn_s_setprio(1);
#pragma unroll
      for (int m = 0; m < 4; ++m)
#pragma unroll
        for (int n = 0; n < 4; ++n)
          acc[4 + m][n] = __builtin_amdgcn_mfma_f32_16x16x32_bf16(af[m], bv[n], acc[4 + m][n], 0, 0, 0);
      __builtin_amdgcn_s_setprio(0);
      if (t < 14)       { asm volatile("s_waitcnt vmcnt(6)" ::: "memory"); }
      else if (t == 14) { asm volatile("s_waitcnt vmcnt(4)" ::: "memory"); }
      __builtin_amdgcn_s_barrier();
    }
  }
#undef STAGE_HALF

#pragma unroll
  for (int gm = 0; gm < 8; ++gm) {
#pragma unroll
    for (int n = 0; n < 4; ++n) {
      int r0 = rowBase + wm * 128 + gm * 16 + (lane >> 4) * 4;
      int c  = colBase + wn * 64 + n * 16 + (lane & 15);
#pragma unroll
      for (int reg = 0; reg < 4; ++reg)
        C[(size_t)(r0 + reg) * ldc + c] = f2bf(acc[gm][n][reg]);
    }
  }
}

// ---------------------------------------------------------------- small GEMM (128x128, attr branch)
__launch_bounds__(256, 2)
__global__ void gemm_bf16_k(const short* __restrict__ A0, const short* __restrict__ A1, int lda,
                            const short* __restrict__ Bt0, const short* __restrict__ Bt1, int ldb,
                            short* __restrict__ C0, short* __restrict__ C1, int ldc, int K,
                            int nbCol, int nbRow) {
  __shared__ short As[128 * 64];
  __shared__ short Bs[128 * 64];

  int orig = blockIdx.x;
  int nwg = gridDim.x;
  int q = nwg >> 3, rr = nwg & 7;
  int xcd = orig & 7, idx = orig >> 3;
  int wg = (xcd < rr ? xcd * (q + 1) : rr * (q + 1) + (xcd - rr) * q) + idx;
  int colB = wg % nbCol;
  int t2   = wg / nbCol;
  int rowB = t2 % nbRow;
  int z    = t2 / nbRow;

  const short* A  = z ? A1 : A0;
  const short* Bt = z ? Bt1 : Bt0;
  short* C        = z ? C1 : C0;

  const int tid  = threadIdx.x;
  const int lane = tid & 63;
  const int wid  = tid >> 6;
  const int wr   = wid >> 1;
  const int wc   = wid & 1;
  const int rowBase = rowB * 128;
  const int colBase = colB * 128;

  const int lrow = lane >> 3;
  const int kofs = (lane & 7) * 8;

  f32x4 acc[4][4];
#pragma unroll
  for (int m = 0; m < 4; ++m)
#pragma unroll
    for (int n = 0; n < 4; ++n)
      acc[m][n] = (f32x4){0.f, 0.f, 0.f, 0.f};

  for (int k0 = 0; k0 < K; k0 += 64) {
#pragma unroll
    for (int c = 0; c < 4; ++c) {
      int chunk = wid * 4 + c;
      int r = chunk * 8 + lrow;
      const short* g = A + (size_t)(rowBase + r) * lda + k0 + kofs;
      GLDS16(g, &As[chunk * 8 * 64]);
    }
#pragma unroll
    for (int c = 0; c < 4; ++c) {
      int chunk = wid * 4 + c;
      int r = chunk * 8 + lrow;
      const short* g = Bt + (size_t)(colBase + r) * ldb + k0 + kofs;
      GLDS16(g, &Bs[chunk * 8 * 64]);
    }
    __syncthreads();

    bf16x8 af[2][4], bfr[2][4];
#pragma unroll
    for (int kk = 0; kk < 2; ++kk) {
#pragma unroll
      for (int i = 0; i < 4; ++i) {
        int ar = wr * 64 + i * 16 + (lane & 15);
        af[kk][i]  = *(const bf16x8*)&As[ar * 64 + kk * 32 + (lane >> 4) * 8];
        int br = wc * 64 + i * 16 + (lane & 15);
        bfr[kk][i] = *(const bf16x8*)&Bs[br * 64 + kk * 32 + (lane >> 4) * 8];
      }
    }
#pragma unroll
    for (int kk = 0; kk < 2; ++kk)
#pragma unroll
      for (int m = 0; m < 4; ++m)
#pragma unroll
        for (int n = 0; n < 4; ++n)
          acc[m][n] = __builtin_amdgcn_mfma_f32_16x16x32_bf16(
              af[kk][m], bfr[kk][n], acc[m][n], 0, 0, 0);
    __syncthreads();
  }

#pragma unroll
  for (int m = 0; m < 4; ++m) {
#pragma unroll
    for (int n = 0; n < 4; ++n) {
      int row0 = rowBase + wr * 64 + m * 16 + (lane >> 4) * 4;
      int col  = colBase + wc * 64 + n * 16 + (lane & 15);
#pragma unroll
      for (int reg = 0; reg < 4; ++reg)
        C[(size_t)(row0 + reg) * ldc + col] = f2bf(acc[m][n][reg]);
    }
  }
}

// ---------------------------------------------------------------- structural SpMM v7: 16 x 64-col chunks
// Chunk slice = 20224 x 64 x 2B = 2.58 MB -> fits one XCD's 4 MB L2.
// XCD x (= orig&7, round-robin dispatch) processes chunk x for both graphs,
// THEN chunk x+8 -- one slice hot at a time. 32 rows/block, 8 lanes x 8 bf16/row.
__launch_bounds__(256)
__global__ void spmm_v7(const int* __restrict__ po0, const int* __restrict__ po1,
                        const int2* __restrict__ pk0, const int2* __restrict__ pk1,
                        const short* __restrict__ S0, const short* __restrict__ S1, int ldS,
                        short* __restrict__ oB0, short* __restrict__ oB1, int ldB) {
  int orig = blockIdx.x;              // 16 * 2 * NRB32 = 20000 blocks (%8==0)
  int x = orig & 7;                   // XCD
  int idx = orig >> 3;                // 0..2499 sequential per XCD
  int sub = idx / (2 * NRB32);        // 0,1: phase
  int rem = idx - sub * (2 * NRB32);
  int graph = rem / NRB32;
  int rowBlk = rem - graph * NRB32;
  int chunk = x + 8 * sub;

  const int* poffs   = graph ? po1 : po0;
  const int2* packed = graph ? pk1 : pk0;
  const short* S     = graph ? S1 : S0;
  short* outB        = graph ? oB1 : oB0;

  const int lane8  = threadIdx.x & 7;
  const int rowloc = threadIdx.x >> 3;        // 0..31
  const int r  = rowBlk * 32 + rowloc;        // NRB32*32 == 20000
  const int c0 = chunk * 64 + lane8 * 8;

  int e0 = poffs[r], e1 = poffs[r + 1];
  float acc[8];
#pragma unroll
  for (int j = 0; j < 8; ++j) acc[j] = 0.f;

  for (int i = e0; i < e1; i += 4) {
    const int4* p4 = (const int4*)&packed[i];
    int4 a = p4[0];
    int4 b = p4[1];
    short8v s0 = *(const short8v*)&S[(size_t)a.x * ldS + c0];
    short8v s1 = *(const short8v*)&S[(size_t)a.z * ldS + c0];
    short8v s2 = *(const short8v*)&S[(size_t)b.x * ldS + c0];
    short8v s3 = *(const short8v*)&S[(size_t)b.z * ldS + c0];
    float v0 = __int_as_float(a.y);
    float v1 = __int_as_float(a.w);
    float v2 = __int_as_float(b.y);
    float v3 = __int_as_float(b.w);
#pragma unroll
    for (int j = 0; j < 8; ++j) {
      acc[j] += v0 * bf2f(s0[j]);
      acc[j] += v1 * bf2f(s1[j]);
      acc[j] += v2 * bf2f(s2[j]);
      acc[j] += v3 * bf2f(s3[j]);
    }
  }
  short8v o;
#pragma unroll
  for (int j = 0; j < 8; ++j) o[j] = f2bf(fmaxf(acc[j], 0.f));
  *(short8v*)&outB[(size_t)r * ldB + c0] = o;
}

// ---------------------------------------------------------------- attr SpMM (v5 NCHUNK=1 semantics)
template<int MODE>
__launch_bounds__(256)
__global__ void spmm_attr(const int* __restrict__ po0, const int* __restrict__ po1,
                          const int2* __restrict__ pk0, const int2* __restrict__ pk1,
                          const short* __restrict__ S0, const short* __restrict__ S1, int ldS,
                          short* __restrict__ oB0, short* __restrict__ oB1, int ldB,
                          float* __restrict__ oF0, float* __restrict__ oF1, int outCols) {
  int orig = blockIdx.x;
  int graph = orig / NRB;
  int rowBlk = orig - graph * NRB;
  const int* poffs   = graph ? po1 : po0;
  const int2* packed = graph ? pk1 : pk0;
  const short* S     = graph ? S1 : S0;
  short* outB        = graph ? oB1 : oB0;
  float* outF        = graph ? oF1 : oF0;

  const int lane16 = threadIdx.x & 15;
  const int rowloc = threadIdx.x >> 4;
  const int r  = rowBlk * 16 + rowloc;
  const int c0 = lane16 * 8;

  int e0 = poffs[r], e1 = poffs[r + 1];
  float acc[8];
#pragma unroll
  for (int j = 0; j < 8; ++j) acc[j] = 0.f;

  for (int i = e0; i < e1; i += 4) {
    const int4* p4 = (const int4*)&packed[i];
    int4 a = p4[0];
    int4 b = p4[1];
    short8v s0 = *(const short8v*)&S[(size_t)a.x * ldS + c0];
    short8v s1 = *(const short8v*)&S[(size_t)a.z * ldS + c0];
    short8v s2 = *(const short8v*)&S[(size_t)b.x * ldS + c0];
    short8v s3 = *(const short8v*)&S[(size_t)b.z * ldS + c0];
    float v0 = __int_as_float(a.y);
    float v1 = __int_as_float(a.w);
    float v2 = __int_as_float(b.y);
    float v3 = __int_as_float(b.w);
#pragma unroll
    for (int j = 0; j < 8; ++j) {
      acc[j] += v0 * bf2f(s0[j]);
      acc[j] += v1 * bf2f(s1[j]);
      acc[j] += v2 * bf2f(s2[j]);
      acc[j] += v3 * bf2f(s3[j]);
    }
  }
#pragma unroll
  for (int j = 0; j < 8; ++j) acc[j] = fmaxf(acc[j], 0.f);

  if (MODE == 0) {
    short8v o;
#pragma unroll
    for (int j = 0; j < 8; ++j) o[j] = f2bf(acc[j]);
    *(short8v*)&outB[(size_t)r * ldB + c0] = o;
  } else {
#pragma unroll
    for (int j = 0; j < 8; ++j)
      if (c0 + j < outCols)
        outF[(size_t)r * outCols + c0 + j] = acc[j];
  }
}

// ---------------------------------------------------------------- row l2 norm (z=2), vectorized short4 reads
__launch_bounds__(256)
__global__ void l2norm2_k(const short* __restrict__ H0, const short* __restrict__ H1, int ldH,
                          float* __restrict__ o0, float* __restrict__ o1, int cols) {
  const short* H = blockIdx.y ? H1 : H0;
  float* out = blockIdx.y ? o1 : o0;
  __shared__ float red[4];
  int r = blockIdx.x;
  int t = threadIdx.x;
  short4 v = ((const short4*)(H + (size_t)r * ldH))[t];
  float f0 = bf2f(v.x), f1 = bf2f(v.y), f2 = bf2f(v.z), f3 = bf2f(v.w);
  float s = f0 * f0 + f1 * f1 + f2 * f2 + f3 * f3;
  for (int off = 32; off >= 1; off >>= 1) s += __shfl_down(s, off, 64);
  if ((t & 63) == 0) red[t >> 6] = s;
  __syncthreads();
  float tot = red[0] + red[1] + red[2] + red[3];
  float inv = 1.f / fmaxf(sqrtf(tot), 1e-12f);
  int c0 = t * 4;
  float vals[4] = {f0, f1, f2, f3};
#pragma unroll
  for (int j = 0; j < 4; ++j)
    if (c0 + j < cols)
      out[(size_t)r * cols + c0 + j] = vals[j] * inv;
}

// ---------------------------------------------------------------- launch

extern "C" void kernel_launch(void* const* d_in, const int* in_sizes, int n_in,
                              void* d_out, int out_size, void* d_ws, size_t ws_size,
                              hipStream_t stream) {
  const float* emb_sr  = (const float*)d_in[0];
  const float* emb_tg  = (const float*)d_in[1];
  const float* attr_sr = (const float*)d_in[2];
  const float* attr_tg = (const float*)d_in[3];
  const int*   row_sr  = (const int*)d_in[4];
  const int*   col_sr  = (const int*)d_in[5];
  const float* vals_sr = (const float*)d_in[6];
  const int*   row_tg  = (const int*)d_in[7];
  const int*   col_tg  = (const int*)d_in[8];
  const float* vals_tg = (const float*)d_in[9];
  const float* W_s0    = (const float*)d_in[10];
  const float* W_s1    = (const float*)d_in[11];
  const float* W_a11   = (const float*)d_in[12];
  const float* W_a12   = (const float*)d_in[13];
  const float* W_a2    = (const float*)d_in[14];

  const int N = N_NODES, Dd = D_IN, E = E_EDGES;

  char* ws = (char*)d_ws;
  size_t off = 0;
  auto alloc = [&](size_t bytes) -> void* {
    void* p = ws + off;
    off += (bytes + 255) & ~(size_t)255;
    return p;
  };
  short* X0 = (short*)alloc((size_t)MPAD * DP * 2);
  short* X1 = (short*)alloc((size_t)MPAD * DP * 2);
  short* T0 = (short*)alloc((size_t)MPAD * DP * 2);
  short* T1 = (short*)alloc((size_t)MPAD * DP * 2);
  short* Y0 = (short*)alloc((size_t)MPAD * DP * 2);   // attr bf16 (early convert)
  short* Y1 = (short*)alloc((size_t)MPAD * DP * 2);
  short* Ws0t  = (short*)alloc((size_t)DP * DP * 2);
  short* Ws1t  = (short*)alloc((size_t)DP * DP * 2);
  short* Wa11t = (short*)alloc((size_t)DAP * DP * 2);
  short* Wa12t = (short*)alloc((size_t)DAP * DP * 2);
  short* Wa2t  = (short*)alloc((size_t)DAP * DAP * 2);
  int*  ibuf    = (int*)alloc((size_t)4 * N * 4);
  int2* pack_sr = (int2*)alloc((size_t)PEMAX * 8);
  int2* pack_tg = (int2*)alloc((size_t)PEMAX * 8);
  int*  poffs_sr = (int*)alloc((size_t)(N + 1) * 4);
  int*  poffs_tg = (int*)alloc((size_t)(N + 1) * 4);
  if (off > ws_size) return;

  int* deg_sr = ibuf;
  int* cur_sr = ibuf + N;
  int* deg_tg = ibuf + 2 * N;
  int* cur_tg = ibuf + 3 * N;
  const int ZERO_N = 4 * N + 2 * (PEMAX * 2);

  float* out_sr  = (float*)d_out;
  float* out_tg  = out_sr + (size_t)N * Dd;
  float* out_sra = out_tg + (size_t)N * Dd;
  float* out_tga = out_sra + (size_t)N * DA;

  // ---- padded-CSR build, both graphs batched
  zero_int_k<<<dim3((ZERO_N + 255) / 256), 256, 0, stream>>>(ibuf, ZERO_N);
  hist2_k<<<dim3((2 * E + 255) / 256), 256, 0, stream>>>(row_sr, row_tg, E, deg_sr, deg_tg);
  scan_pad2_k<<<2, SCAN_T, 0, stream>>>(deg_sr, deg_tg, N, poffs_sr, poffs_tg);
  scatter_pack2_k<<<dim3((2 * E + 255) / 256), 256, 0, stream>>>(
      row_sr, col_sr, vals_sr, row_tg, col_tg, vals_tg, E,
      poffs_sr, poffs_tg, cur_sr, cur_tg, pack_sr, pack_tg);

  // ---- all input conversions + weights
  cvt_pad4_v3<<<dim3(1, MPAD / 4, 4), 256, 0, stream>>>(emb_sr, emb_tg, attr_sr, attr_tg,
                                                        X0, X1, Y0, Y1);
  cvt_w_t2_k<<<dim3(DP / 256, DP, 2), 256, 0, stream>>>(W_s0, W_s1, Dd, Dd, Ws0t, Ws1t, DP);
  cvt_w_t2_k<<<dim3(DP / 256, DAP, 2), 256, 0, stream>>>(W_a11, W_a12, Dd, DA, Wa11t, Wa12t, DP);
  cvt_w_t2_k<<<dim3(1, DAP, 1), 256, 0, stream>>>(W_a2, W_a2, DA, DA, Wa2t, Wa2t, DAP);

  // ---- structural branch: 8-phase 256^2 GEMM (79x4x2 = 632 blocks)
  gemm8p_k<<<dim3(79 * 4 * 2), 512, 0, stream>>>(X0, X1, DP, Ws0t, Ws0t, DP,
                                                 T0, T1, DP, 4, 79);
  spmm_v7<<<dim3(16 * 2 * NRB32), 256, 0, stream>>>(
      poffs_sr, poffs_tg, pack_sr, pack_tg, T0, T1, DP, X0, X1, DP);
  gemm8p_k<<<dim3(79 * 4 * 2), 512, 0, stream>>>(X0, X1, DP, Ws1t, Ws1t, DP,
                                                 T0, T1, DP, 4, 79);
  spmm_v7<<<dim3(16 * 2 * NRB32), 256, 0, stream>>>(
      poffs_sr, poffs_tg, pack_sr, pack_tg, T0, T1, DP, X0, X1, DP);
  l2norm2_k<<<dim3(N, 2), 256, 0, stream>>>(X0, X1, DP, out_sr, out_tg, Dd);

  // ---- attribute branch (A = Y, pre-converted; compact stride DAP)
  gemm_bf16_k<<<dim3(1 * MBLK * 2), 256, 0, stream>>>(Y0, Y1, DP, Wa11t, Wa12t, DP,
                                                      T0, T1, DAP, DP, 1, MBLK);
  spmm_attr<0><<<dim3(2 * NRB), 256, 0, stream>>>(
      poffs_sr, poffs_tg, pack_sr, pack_tg, T0, T1, DAP, X0, X1, DAP, nullptr, nullptr, 0);
  gemm_bf16_k<<<dim3(1 * MBLK * 2), 256, 0, stream>>>(X0, X1, DAP, Wa2t, Wa2t, DAP,
                                                      T0, T1, DAP, DAP, 1, MBLK);
  spmm_attr<1><<<dim3(2 * NRB), 256, 0, stream>>>(
      poffs_sr, poffs_tg, pack_sr, pack_tg, T0, T1, DAP, nullptr, nullptr, 0, out_sra, out_tga, DA);
}

// Round 15
// 633.213 us; speedup vs baseline: 1.0729x; 1.0173x over previous
//
#include <hip/hip_runtime.h>

#define N_NODES 20000
#define D_IN    1000
#define E_EDGES 160000
#define DA      100

#define MPAD 20224    // 79 * 256 (padded rows for 256-tile GEMM)
#define DP   1024     // padded K / structural cols
#define DAP  128      // padded attr cols
#define MBLK 157      // 128-row blocks for attr gemm
#define NRB  1250     // row-blocks per graph for spmm (16 rows/block)
#define PEMAX (E_EDGES + 4 * N_NODES)   // padded edge capacity (rows padded to x4)

typedef __bf16 bf16x8 __attribute__((ext_vector_type(8)));
typedef float  f32x4  __attribute__((ext_vector_type(4)));
typedef short  short8v __attribute__((ext_vector_type(8)));

__device__ __forceinline__ short f2bf(float f) {
  __bf16 h = (__bf16)f;                 // native RNE cvt
  return *(short*)&h;
}
__device__ __forceinline__ float bf2f(short s) {
  return __uint_as_float(((unsigned)(unsigned short)s) << 16);
}

#define GLDS16(g, l) __builtin_amdgcn_global_load_lds( \
    (const __attribute__((address_space(1))) void*)(g), \
    (__attribute__((address_space(3))) void*)(l), 16, 0, 0)

// ---------------------------------------------------------------- conversions

// batched (z=4) f32->bf16 pad, float4 loads. grid: (1, MPAD, 4), 256 thr (r9 best)
__global__ void cvt_pad4_k(const float* __restrict__ s0, const float* __restrict__ s1,
                           const float* __restrict__ s2, const float* __restrict__ s3,
                           int R, int C,
                           short* __restrict__ d0, short* __restrict__ d1,
                           short* __restrict__ d2, short* __restrict__ d3, int Cp) {
  const float* src; short* dst;
  switch (blockIdx.z) {
    case 0:  src = s0; dst = d0; break;
    case 1:  src = s1; dst = d1; break;
    case 2:  src = s2; dst = d2; break;
    default: src = s3; dst = d3; break;
  }
  int r = blockIdx.y;
  int c0 = threadIdx.x * 4;
  short4 o = {0, 0, 0, 0};
  if (r < R) {
    if (c0 + 3 < C) {
      float4 v = *(const float4*)&src[(size_t)r * C + c0];
      o.x = f2bf(v.x); o.y = f2bf(v.y); o.z = f2bf(v.z); o.w = f2bf(v.w);
    } else {
#pragma unroll
      for (int j = 0; j < 4; ++j) {
        float v = (c0 + j < C) ? src[(size_t)r * C + c0 + j] : 0.f;
        ((short*)&o)[j] = f2bf(v);
      }
    }
  }
  *(short4*)&dst[(size_t)r * Cp + c0] = o;
}

__global__ void cvt_w_t2_k(const float* __restrict__ s0, const float* __restrict__ s1,
                           int K, int Nc,
                           short* __restrict__ d0, short* __restrict__ d1, int Kp) {
  const float* src = blockIdx.z ? s1 : s0;
  short* dst = blockIdx.z ? d1 : d0;
  int n = blockIdx.y;
  int k = blockIdx.x * blockDim.x + threadIdx.x;
  if (k >= Kp) return;
  float v = (k < K && n < Nc) ? src[(size_t)k * Nc + n] : 0.f;
  dst[(size_t)n * Kp + k] = f2bf(v);
}

__global__ void zero_int_k(int* p, int n) {
  int i = blockIdx.x * blockDim.x + threadIdx.x;
  if (i < n) p[i] = 0;
}

// ---------------------------------------------------------------- CSR build (padded, both graphs)

__global__ void hist2_k(const int* __restrict__ row0, const int* __restrict__ row1, int E,
                        int* __restrict__ deg0, int* __restrict__ deg1) {
  int e = blockIdx.x * blockDim.x + threadIdx.x;
  if (e < E) atomicAdd(&deg0[row0[e]], 1);
  else if (e < 2 * E) atomicAdd(&deg1[row1[e - E]], 1);
}

#define SCAN_T 1024
#define SCAN_C 20
__launch_bounds__(SCAN_T)
__global__ void scan_pad2_k(const int* __restrict__ dg0, const int* __restrict__ dg1, int n,
                            int* __restrict__ p0, int* __restrict__ p1) {
  const int* deg = blockIdx.x ? dg1 : dg0;
  int* poffs = blockIdx.x ? p1 : p0;
  __shared__ int lds[SCAN_T];
  int t = threadIdx.x;
  int base = t * SCAN_C;
  int v[SCAN_C];
  int s = 0;
#pragma unroll
  for (int i = 0; i < SCAN_C; ++i) {
    int idx = base + i;
    int x = (idx < n) ? ((deg[idx] + 3) & ~3) : 0;
    s += x;
    v[i] = s;
  }
  lds[t] = s;
  __syncthreads();
  for (int off = 1; off < SCAN_T; off <<= 1) {
    int add = (t >= off) ? lds[t - off] : 0;
    __syncthreads();
    lds[t] += add;
    __syncthreads();
  }
  int prefix = lds[t] - s;
#pragma unroll
  for (int i = 0; i < SCAN_C; ++i) {
    int idx = base + i;
    if (idx < n) poffs[idx + 1] = v[i] + prefix;
  }
  if (t == 0) poffs[0] = 0;
}

__global__ void scatter_pack2_k(const int* __restrict__ row0, const int* __restrict__ col0,
                                const float* __restrict__ val0,
                                const int* __restrict__ row1, const int* __restrict__ col1,
                                const float* __restrict__ val1, int E,
                                const int* __restrict__ po0, const int* __restrict__ po1,
                                int* __restrict__ cur0, int* __restrict__ cur1,
                                int2* __restrict__ pk0, int2* __restrict__ pk1) {
  int e = blockIdx.x * blockDim.x + threadIdx.x;
  if (e < E) {
    int r = row0[e];
    int p = atomicAdd(&cur0[r], 1);
    pk0[po0[r] + p] = make_int2(col0[e], __float_as_int(val0[e]));
  } else if (e < 2 * E) {
    int ee = e - E;
    int r = row1[ee];
    int p = atomicAdd(&cur1[r], 1);
    pk1[po1[r] + p] = make_int2(col1[ee], __float_as_int(val1[ee]));
  }
}

// ---------------------------------------------------------------- 8-phase 256x256 GEMM (structural, r9 best)
__launch_bounds__(512, 1)
__global__ void gemm8p_k(const short* __restrict__ A0, const short* __restrict__ A1, int lda,
                         const short* __restrict__ Bt0, const short* __restrict__ Bt1, int ldb,
                         short* __restrict__ C0, short* __restrict__ C1, int ldc,
                         int nbCol, int nbRow) {
  __shared__ short lds[8][8192];   // 8 x 16 KB = 128 KB

  int orig = blockIdx.x;
  int nwg = gridDim.x;
  int q = nwg >> 3, rr = nwg & 7;
  int xcd = orig & 7, idx = orig >> 3;
  int wg = (xcd < rr ? xcd * (q + 1) : rr * (q + 1) + (xcd - rr) * q) + idx;
  int colB = wg % nbCol;
  int t2 = wg / nbCol;
  int rowB = t2 % nbRow;
  int z = t2 / nbRow;

  const short* A  = z ? A1 : A0;
  const short* Bt = z ? Bt1 : Bt0;
  short* C        = z ? C1 : C0;

  const int tid  = threadIdx.x;
  const int lane = tid & 63;
  const int wid  = tid >> 6;
  const int wm   = wid >> 2;
  const int wn   = wid & 3;
  const int rowBase = rowB * 256;
  const int colBase = colB * 256;

  const int sC = (lane & 3) ^ ((lane >> 3) & 3);
  const short* baseA = A  + (size_t)(rowBase + wid * 32 + (lane >> 2)) * lda + sC * 8;
  const short* baseB = Bt + (size_t)(colBase + wid * 32 + (lane >> 2)) * ldb + sC * 8;

  const int chunkR = (lane >> 4) ^ ((lane >> 1) & 3);
  const int offA = (wm * 128 + (lane & 15)) * 32 + chunkR * 8;
  const int offB = (wn * 64  + (lane & 15)) * 32 + chunkR * 8;

  f32x4 acc[8][4];
#pragma unroll
  for (int m = 0; m < 8; ++m)
#pragma unroll
    for (int n = 0; n < 4; ++n)
      acc[m][n] = (f32x4){0.f, 0.f, 0.f, 0.f};

#define STAGE_HALF(h) do { \
    int tt_ = (h) >> 2; \
    int kc_ = tt_ * 64 + (((h) >> 1) & 1) * 32; \
    short* dst_ = &lds[(h) & 7][wid * 1024]; \
    if ((h) & 1) { GLDS16(baseB + kc_, dst_); GLDS16(baseB + kc_ + 16 * ldb, dst_ + 512); } \
    else         { GLDS16(baseA + kc_, dst_); GLDS16(baseA + kc_ + 16 * lda, dst_ + 512); } \
  } while (0)

  STAGE_HALF(0); STAGE_HALF(1); STAGE_HALF(2); STAGE_HALF(3); STAGE_HALF(4);
  asm volatile("s_waitcnt vmcnt(6)" ::: "memory");
  __builtin_amdgcn_s_barrier();

  bf16x8 bv[4];
  for (int t = 0; t < 16; ++t) {
    const int s0 = (4 * t) & 7;
    const int s1 = (4 * t + 2) & 7;

    { // P0: ks=0, qm=0
      const short* pA = &lds[s0][0];
      const short* pB = &lds[s0 + 1][0];
      bf16x8 af[4];
#pragma unroll
      for (int n = 0; n < 4; ++n) bv[n] = *(const bf16x8*)&pB[offB + n * 512];
#pragma unroll
      for (int m = 0; m < 4; ++m) af[m] = *(const bf16x8*)&pA[offA + m * 512];
      { int h = 4 * t + 5; if (h < 64) STAGE_HALF(h); }
      __builtin_amdgcn_s_barrier();
      __builtin_amdgcn_s_setprio(1);
#pragma unroll
      for (int m = 0; m < 4; ++m)
#pragma unroll
        for (int n = 0; n < 4; ++n)
          acc[m][n] = __builtin_amdgcn_mfma_f32_16x16x32_bf16(af[m], bv[n], acc[m][n], 0, 0, 0);
      __builtin_amdgcn_s_setprio(0);
      __builtin_amdgcn_s_barrier();
    }
    { // P1: ks=0, qm=1 (B from regs)
      const short* pA = &lds[s0][0];
      bf16x8 af[4];
#pragma unroll
      for (int m = 0; m < 4; ++m) af[m] = *(const bf16x8*)&pA[offA + (4 + m) * 512];
      { int h = 4 * t + 6; if (h < 64) STAGE_HALF(h); }
      __builtin_amdgcn_s_barrier();
      __builtin_amdgcn_s_setprio(1);
#pragma unroll
      for (int m = 0; m < 4; ++m)
#pragma unroll
        for (int n = 0; n < 4; ++n)
          acc[4 + m][n] = __builtin_amdgcn_mfma_f32_16x16x32_bf16(af[m], bv[n], acc[4 + m][n], 0, 0, 0);
      __builtin_amdgcn_s_setprio(0);
      if (t < 15) { asm volatile("s_waitcnt vmcnt(6)" ::: "memory"); }
      else        { asm volatile("s_waitcnt vmcnt(0)" ::: "memory"); }
      __builtin_amdgcn_s_barrier();
    }
    { // P2: ks=1, qm=0
      const short* pA = &lds[s1][0];
      const short* pB = &lds[s1 + 1][0];
      bf16x8 af[4];
#pragma unroll
      for (int n = 0; n < 4; ++n) bv[n] = *(const bf16x8*)&pB[offB + n * 512];
#pragma unroll
      for (int m = 0; m < 4; ++m) af[m] = *(const bf16x8*)&pA[offA + m * 512];
      { int h = 4 * t + 7; if (h < 64) STAGE_HALF(h); }
      __builtin_amdgcn_s_barrier();
      __builtin_amdgcn_s_setprio(1);
#pragma unroll
      for (int m = 0; m < 4; ++m)
#pragma unroll
        for (int n = 0; n < 4; ++n)
          acc[m][n] = __builtin_amdgcn_mfma_f32_16x16x32_bf16(af[m], bv[n], acc[m][n], 0, 0, 0);
      __builtin_amdgcn_s_setprio(0);
      __builtin_amdgcn_s_barrier();
    }
    { // P3: ks=1, qm=1
      const short* pA = &lds[s1][0];
      bf16x8 af[4];
#pragma unroll
      for (int m = 0; m < 4; ++m) af[m] = *(const bf16x8*)&pA[offA + (4 + m) * 512];
      { int h = 4 * t + 8; if (h < 64) STAGE_HALF(h); }
      __builtin_amdgcn_s_barrier();
      __builtin_amdgcn_s_setprio(1);
#pragma unroll
      for (int m = 0; m < 4; ++m)
#pragma unroll
        for (int n = 0; n < 4; ++n)
          acc[4 + m][n] = __builtin_amdgcn_mfma_f32_16x16x32_bf16(af[m], bv[n], acc[4 + m][n], 0, 0, 0);
      __builtin_amdgcn_s_setprio(0);
      if (t < 14)       { asm volatile("s_waitcnt vmcnt(6)" ::: "memory"); }
      else if (t == 14) { asm volatile("s_waitcnt vmcnt(4)" ::: "memory"); }
      __builtin_amdgcn_s_barrier();
    }
  }
#undef STAGE_HALF

#pragma unroll
  for (int gm = 0; gm < 8; ++gm) {
#pragma unroll
    for (int n = 0; n < 4; ++n) {
      int r0 = rowBase + wm * 128 + gm * 16 + (lane >> 4) * 4;
      int c  = colBase + wn * 64 + n * 16 + (lane & 15);
#pragma unroll
      for (int reg = 0; reg < 4; ++reg)
        C[(size_t)(r0 + reg) * ldc + c] = f2bf(acc[gm][n][reg]);
    }
  }
}

// ---------------------------------------------------------------- small GEMM (128x128, attr branch)
__launch_bounds__(256, 2)
__global__ void gemm_bf16_k(const short* __restrict__ A0, const short* __restrict__ A1, int lda,
                            const short* __restrict__ Bt0, const short* __restrict__ Bt1, int ldb,
                            short* __restrict__ C0, short* __restrict__ C1, int ldc, int K,
                            int nbCol, int nbRow) {
  __shared__ short As[128 * 64];
  __shared__ short Bs[128 * 64];

  int orig = blockIdx.x;
  int nwg = gridDim.x;
  int q = nwg >> 3, rr = nwg & 7;
  int xcd = orig & 7, idx = orig >> 3;
  int wg = (xcd < rr ? xcd * (q + 1) : rr * (q + 1) + (xcd - rr) * q) + idx;
  int colB = wg % nbCol;
  int t2   = wg / nbCol;
  int rowB = t2 % nbRow;
  int z    = t2 / nbRow;

  const short* A  = z ? A1 : A0;
  const short* Bt = z ? Bt1 : Bt0;
  short* C        = z ? C1 : C0;

  const int tid  = threadIdx.x;
  const int lane = tid & 63;
  const int wid  = tid >> 6;
  const int wr   = wid >> 1;
  const int wc   = wid & 1;
  const int rowBase = rowB * 128;
  const int colBase = colB * 128;

  const int lrow = lane >> 3;
  const int kofs = (lane & 7) * 8;

  f32x4 acc[4][4];
#pragma unroll
  for (int m = 0; m < 4; ++m)
#pragma unroll
    for (int n = 0; n < 4; ++n)
      acc[m][n] = (f32x4){0.f, 0.f, 0.f, 0.f};

  for (int k0 = 0; k0 < K; k0 += 64) {
#pragma unroll
    for (int c = 0; c < 4; ++c) {
      int chunk = wid * 4 + c;
      int r = chunk * 8 + lrow;
      const short* g = A + (size_t)(rowBase + r) * lda + k0 + kofs;
      GLDS16(g, &As[chunk * 8 * 64]);
    }
#pragma unroll
    for (int c = 0; c < 4; ++c) {
      int chunk = wid * 4 + c;
      int r = chunk * 8 + lrow;
      const short* g = Bt + (size_t)(colBase + r) * ldb + k0 + kofs;
      GLDS16(g, &Bs[chunk * 8 * 64]);
    }
    __syncthreads();

    bf16x8 af[2][4], bfr[2][4];
#pragma unroll
    for (int kk = 0; kk < 2; ++kk) {
#pragma unroll
      for (int i = 0; i < 4; ++i) {
        int ar = wr * 64 + i * 16 + (lane & 15);
        af[kk][i]  = *(const bf16x8*)&As[ar * 64 + kk * 32 + (lane >> 4) * 8];
        int br = wc * 64 + i * 16 + (lane & 15);
        bfr[kk][i] = *(const bf16x8*)&Bs[br * 64 + kk * 32 + (lane >> 4) * 8];
      }
    }
#pragma unroll
    for (int kk = 0; kk < 2; ++kk)
#pragma unroll
      for (int m = 0; m < 4; ++m)
#pragma unroll
        for (int n = 0; n < 4; ++n)
          acc[m][n] = __builtin_amdgcn_mfma_f32_16x16x32_bf16(
              af[kk][m], bfr[kk][n], acc[m][n], 0, 0, 0);
    __syncthreads();
  }

#pragma unroll
  for (int m = 0; m < 4; ++m) {
#pragma unroll
    for (int n = 0; n < 4; ++n) {
      int row0 = rowBase + wr * 64 + m * 16 + (lane >> 4) * 4;
      int col  = colBase + wc * 64 + n * 16 + (lane & 15);
#pragma unroll
      for (int reg = 0; reg < 4; ++reg)
        C[(size_t)(row0 + reg) * ldc + col] = f2bf(acc[m][n][reg]);
    }
  }
}

// ---------------------------------------------------------------- SpMM + ReLU (v5: col-chunked, XCD-pinned, r9 best)
template<int NCHUNK, int MODE>
__launch_bounds__(256)
__global__ void spmm_v5(const int* __restrict__ po0, const int* __restrict__ po1,
                        const int2* __restrict__ pk0, const int2* __restrict__ pk1,
                        const short* __restrict__ S0, const short* __restrict__ S1, int ldS,
                        short* __restrict__ oB0, short* __restrict__ oB1, int ldB,
                        float* __restrict__ oF0, float* __restrict__ oF1, int outCols) {
  int orig = blockIdx.x;
  int chunk, graph, rowBlk;
  if (NCHUNK == 8) {
    chunk = orig & 7;
    int idx = orig >> 3;
    graph = idx / NRB;
    rowBlk = idx - graph * NRB;
  } else {
    chunk = 0;
    graph = orig / NRB;
    rowBlk = orig - graph * NRB;
  }
  const int* poffs   = graph ? po1 : po0;
  const int2* packed = graph ? pk1 : pk0;
  const short* S     = graph ? S1 : S0;
  short* outB        = graph ? oB1 : oB0;
  float* outF        = graph ? oF1 : oF0;

  const int lane16 = threadIdx.x & 15;
  const int rowloc = threadIdx.x >> 4;
  const int r  = rowBlk * 16 + rowloc;
  const int c0 = chunk * 128 + lane16 * 8;

  int e0 = poffs[r], e1 = poffs[r + 1];
  float acc[8];
#pragma unroll
  for (int j = 0; j < 8; ++j) acc[j] = 0.f;

  for (int i = e0; i < e1; i += 4) {
    const int4* p4 = (const int4*)&packed[i];
    int4 a = p4[0];
    int4 b = p4[1];
    short8v s0 = *(const short8v*)&S[(size_t)a.x * ldS + c0];
    short8v s1 = *(const short8v*)&S[(size_t)a.z * ldS + c0];
    short8v s2 = *(const short8v*)&S[(size_t)b.x * ldS + c0];
    short8v s3 = *(const short8v*)&S[(size_t)b.z * ldS + c0];
    float v0 = __int_as_float(a.y);
    float v1 = __int_as_float(a.w);
    float v2 = __int_as_float(b.y);
    float v3 = __int_as_float(b.w);
#pragma unroll
    for (int j = 0; j < 8; ++j) {
      acc[j] += v0 * bf2f(s0[j]);
      acc[j] += v1 * bf2f(s1[j]);
      acc[j] += v2 * bf2f(s2[j]);
      acc[j] += v3 * bf2f(s3[j]);
    }
  }
#pragma unroll
  for (int j = 0; j < 8; ++j) acc[j] = fmaxf(acc[j], 0.f);

  if (MODE == 0) {
    short8v o;
#pragma unroll
    for (int j = 0; j < 8; ++j) o[j] = f2bf(acc[j]);
    *(short8v*)&outB[(size_t)r * ldB + c0] = o;
  } else {
#pragma unroll
    for (int j = 0; j < 8; ++j)
      if (c0 + j < outCols)
        outF[(size_t)r * outCols + c0 + j] = acc[j];
  }
}

// ---------------------------------------------------------------- row l2 norm (z=2), vectorized short4 reads
__launch_bounds__(256)
__global__ void l2norm2_k(const short* __restrict__ H0, const short* __restrict__ H1, int ldH,
                          float* __restrict__ o0, float* __restrict__ o1, int cols) {
  const short* H = blockIdx.y ? H1 : H0;
  float* out = blockIdx.y ? o1 : o0;
  __shared__ float red[4];
  int r = blockIdx.x;
  int t = threadIdx.x;
  short4 v = ((const short4*)(H + (size_t)r * ldH))[t];
  float f0 = bf2f(v.x), f1 = bf2f(v.y), f2 = bf2f(v.z), f3 = bf2f(v.w);
  float s = f0 * f0 + f1 * f1 + f2 * f2 + f3 * f3;
  for (int off = 32; off >= 1; off >>= 1) s += __shfl_down(s, off, 64);
  if ((t & 63) == 0) red[t >> 6] = s;
  __syncthreads();
  float tot = red[0] + red[1] + red[2] + red[3];
  float inv = 1.f / fmaxf(sqrtf(tot), 1e-12f);
  int c0 = t * 4;
  float vals[4] = {f0, f1, f2, f3};
#pragma unroll
  for (int j = 0; j < 4; ++j)
    if (c0 + j < cols)
      out[(size_t)r * cols + c0 + j] = vals[j] * inv;
}

// ---------------------------------------------------------------- launch

extern "C" void kernel_launch(void* const* d_in, const int* in_sizes, int n_in,
                              void* d_out, int out_size, void* d_ws, size_t ws_size,
                              hipStream_t stream) {
  const float* emb_sr  = (const float*)d_in[0];
  const float* emb_tg  = (const float*)d_in[1];
  const float* attr_sr = (const float*)d_in[2];
  const float* attr_tg = (const float*)d_in[3];
  const int*   row_sr  = (const int*)d_in[4];
  const int*   col_sr  = (const int*)d_in[5];
  const float* vals_sr = (const float*)d_in[6];
  const int*   row_tg  = (const int*)d_in[7];
  const int*   col_tg  = (const int*)d_in[8];
  const float* vals_tg = (const float*)d_in[9];
  const float* W_s0    = (const float*)d_in[10];
  const float* W_s1    = (const float*)d_in[11];
  const float* W_a11   = (const float*)d_in[12];
  const float* W_a12   = (const float*)d_in[13];
  const float* W_a2    = (const float*)d_in[14];

  const int N = N_NODES, Dd = D_IN, E = E_EDGES;

  char* ws = (char*)d_ws;
  size_t off = 0;
  auto alloc = [&](size_t bytes) -> void* {
    void* p = ws + off;
    off += (bytes + 255) & ~(size_t)255;
    return p;
  };
  short* X0 = (short*)alloc((size_t)MPAD * DP * 2);
  short* X1 = (short*)alloc((size_t)MPAD * DP * 2);
  short* T0 = (short*)alloc((size_t)MPAD * DP * 2);
  short* T1 = (short*)alloc((size_t)MPAD * DP * 2);
  short* Y0 = (short*)alloc((size_t)MPAD * DP * 2);   // attr bf16 (early convert)
  short* Y1 = (short*)alloc((size_t)MPAD * DP * 2);
  short* Ws0t  = (short*)alloc((size_t)DP * DP * 2);
  short* Ws1t  = (short*)alloc((size_t)DP * DP * 2);
  short* Wa11t = (short*)alloc((size_t)DAP * DP * 2);
  short* Wa12t = (short*)alloc((size_t)DAP * DP * 2);
  short* Wa2t  = (short*)alloc((size_t)DAP * DAP * 2);
  int*  ibuf    = (int*)alloc((size_t)4 * N * 4);
  int2* pack_sr = (int2*)alloc((size_t)PEMAX * 8);
  int2* pack_tg = (int2*)alloc((size_t)PEMAX * 8);
  int*  poffs_sr = (int*)alloc((size_t)(N + 1) * 4);
  int*  poffs_tg = (int*)alloc((size_t)(N + 1) * 4);
  if (off > ws_size) return;

  int* deg_sr = ibuf;
  int* cur_sr = ibuf + N;
  int* deg_tg = ibuf + 2 * N;
  int* cur_tg = ibuf + 3 * N;
  const int ZERO_N = 4 * N + 2 * (PEMAX * 2);

  float* out_sr  = (float*)d_out;
  float* out_tg  = out_sr + (size_t)N * Dd;
  float* out_sra = out_tg + (size_t)N * Dd;
  float* out_tga = out_sra + (size_t)N * DA;

  // ---- padded-CSR build, both graphs batched
  zero_int_k<<<dim3((ZERO_N + 255) / 256), 256, 0, stream>>>(ibuf, ZERO_N);
  hist2_k<<<dim3((2 * E + 255) / 256), 256, 0, stream>>>(row_sr, row_tg, E, deg_sr, deg_tg);
  scan_pad2_k<<<2, SCAN_T, 0, stream>>>(deg_sr, deg_tg, N, poffs_sr, poffs_tg);
  scatter_pack2_k<<<dim3((2 * E + 255) / 256), 256, 0, stream>>>(
      row_sr, col_sr, vals_sr, row_tg, col_tg, vals_tg, E,
      poffs_sr, poffs_tg, cur_sr, cur_tg, pack_sr, pack_tg);

  // ---- all input conversions (z=4 batch) + weights
  cvt_pad4_k<<<dim3(1, MPAD, 4), 256, 0, stream>>>(emb_sr, emb_tg, attr_sr, attr_tg,
                                                   N, Dd, X0, X1, Y0, Y1, DP);
  cvt_w_t2_k<<<dim3(DP / 256, DP, 2), 256, 0, stream>>>(W_s0, W_s1, Dd, Dd, Ws0t, Ws1t, DP);
  cvt_w_t2_k<<<dim3(DP / 256, DAP, 2), 256, 0, stream>>>(W_a11, W_a12, Dd, DA, Wa11t, Wa12t, DP);
  cvt_w_t2_k<<<dim3(1, DAP, 1), 256, 0, stream>>>(W_a2, W_a2, DA, DA, Wa2t, Wa2t, DAP);

  // ---- structural branch: 8-phase 256^2 GEMM (79x4x2 = 632 blocks)
  gemm8p_k<<<dim3(79 * 4 * 2), 512, 0, stream>>>(X0, X1, DP, Ws0t, Ws0t, DP,
                                                 T0, T1, DP, 4, 79);
  spmm_v5<8, 0><<<dim3(8 * 2 * NRB), 256, 0, stream>>>(
      poffs_sr, poffs_tg, pack_sr, pack_tg, T0, T1, DP, X0, X1, DP, nullptr, nullptr, 0);
  gemm8p_k<<<dim3(79 * 4 * 2), 512, 0, stream>>>(X0, X1, DP, Ws1t, Ws1t, DP,
                                                 T0, T1, DP, 4, 79);
  spmm_v5<8, 0><<<dim3(8 * 2 * NRB), 256, 0, stream>>>(
      poffs_sr, poffs_tg, pack_sr, pack_tg, T0, T1, DP, X0, X1, DP, nullptr, nullptr, 0);
  l2norm2_k<<<dim3(N, 2), 256, 0, stream>>>(X0, X1, DP, out_sr, out_tg, Dd);

  // ---- attribute branch (A = Y, pre-converted; compact stride DAP)
  gemm_bf16_k<<<dim3(1 * MBLK * 2), 256, 0, stream>>>(Y0, Y1, DP, Wa11t, Wa12t, DP,
                                                      T0, T1, DAP, DP, 1, MBLK);
  spmm_v5<1, 0><<<dim3(2 * NRB), 256, 0, stream>>>(
      poffs_sr, poffs_tg, pack_sr, pack_tg, T0, T1, DAP, X0, X1, DAP, nullptr, nullptr, 0);
  gemm_bf16_k<<<dim3(1 * MBLK * 2), 256, 0, stream>>>(X0, X1, DAP, Wa2t, Wa2t, DAP,
                                                      T0, T1, DAP, DAP, 1, MBLK);
  spmm_v5<1, 1><<<dim3(2 * NRB), 256, 0, stream>>>(
      poffs_sr, poffs_tg, pack_sr, pack_tg, T0, T1, DAP, nullptr, nullptr, 0, out_sra, out_tga, DA);
}